// Round 7
// baseline (389.122 us; speedup 1.0000x reference)
//
#include <hip/hip_runtime.h>

#define B_  4
#define S_  2048
#define D_  1024
#define H_  16
#define DH_ 64

typedef __attribute__((ext_vector_type(8))) short bf16x8;
typedef __attribute__((ext_vector_type(4))) float f32x4;
typedef __attribute__((ext_vector_type(16))) float f32x16;
typedef __attribute__((ext_vector_type(4))) unsigned short u16x4;

__device__ __forceinline__ unsigned short f2bf(float f) {
  union { float f; unsigned int u; } x; x.f = f;
  unsigned int u = x.u;
  unsigned int r = (u + 0x7fffu + ((u >> 16) & 1u)) >> 16;  // RNE
  return (unsigned short)r;
}

__device__ __forceinline__ int cvtpk(float lo, float hi) {
  unsigned r;
  asm("v_cvt_pk_bf16_f32 %0, %1, %2" : "=v"(r) : "v"(lo), "v"(hi));
  return (int)r;
}

// ---------------- W (fp32 [k][n]) -> Wt (bf16 [n][k]) ----------------
__global__ __launch_bounds__(256) void wtrans_kernel(const float* __restrict__ W0,
                                                     const float* __restrict__ W1,
                                                     const float* __restrict__ W2,
                                                     unsigned short* __restrict__ Wt) {
  __shared__ float t[32][33];
  const int z = blockIdx.z;
  const float* W = (z == 0) ? W0 : ((z == 1) ? W1 : W2);
  unsigned short* O = Wt + (size_t)z * (D_ * D_);
  const int n0 = blockIdx.x * 32, k0 = blockIdx.y * 32;
  const int tx = threadIdx.x, ty = threadIdx.y;
#pragma unroll
  for (int i = 0; i < 4; i++) t[ty + i * 8][tx] = W[(size_t)(k0 + ty + i * 8) * D_ + n0 + tx];
  __syncthreads();
#pragma unroll
  for (int i = 0; i < 4; i++)
    O[(size_t)(n0 + ty + i * 8) * D_ + k0 + tx] = f2bf(t[tx][ty + i * 8]);
}

// ---------------- projection GEMM: Y(bf16) = X(fp32) @ W, via Wt ----------------
// For z==0 (q), folds 0.125*log2e (attn scale, log2 domain) into the output.
__global__ __launch_bounds__(256) void proj_kernel(const float* __restrict__ X0,
                                                   const float* __restrict__ X1,
                                                   const float* __restrict__ X2,
                                                   const unsigned short* __restrict__ Wt,
                                                   unsigned short* __restrict__ Y0) {
  __shared__ unsigned short Alds[128 * 72];
  __shared__ unsigned short Blds[128 * 72];
  const int z = blockIdx.z;
  const float* X = (z == 0) ? X0 : ((z == 1) ? X1 : X2);
  const unsigned short* Wz = Wt + (size_t)z * (D_ * D_);
  unsigned short* Y = Y0 + (size_t)z * ((size_t)B_ * S_ * D_);
  const float osc = (z == 0) ? 0.18033688f : 1.0f;  // 0.125 * log2(e)

  const int tid = threadIdx.x;
  const int lane = tid & 63, w = tid >> 6;
  const int wr = w >> 1, wc = w & 1;
  const int l15 = lane & 15, lg = lane >> 4;
  const int r0 = blockIdx.y * 128, c0 = blockIdx.x * 128;

  f32x4 acc[4][4];
#pragma unroll
  for (int m = 0; m < 4; m++)
#pragma unroll
    for (int n = 0; n < 4; n++) acc[m][n] = (f32x4){0.f, 0.f, 0.f, 0.f};

  for (int kt = 0; kt < 16; ++kt) {
    __syncthreads();
    {
      const int rr = tid >> 4, cf = (tid & 15) * 4;
#pragma unroll
      for (int p = 0; p < 8; p++) {
        int row = rr + p * 16;
        float4 xv = *(const float4*)(X + (size_t)(r0 + row) * D_ + kt * 64 + cf);
        u16x4 bb = { f2bf(xv.x), f2bf(xv.y), f2bf(xv.z), f2bf(xv.w) };
        *(u16x4*)(&Alds[row * 72 + cf]) = bb;
      }
      const int rb = tid >> 3, cb = tid & 7;
#pragma unroll
      for (int p = 0; p < 4; p++) {
        int row = rb + p * 32;
        bf16x8 wv = *(const bf16x8*)(Wz + (size_t)(c0 + row) * D_ + kt * 64 + cb * 8);
        *(bf16x8*)(&Blds[row * 72 + cb * 8]) = wv;
      }
    }
    __syncthreads();

    bf16x8 af[4][2];
#pragma unroll
    for (int m = 0; m < 4; m++)
#pragma unroll
      for (int kc = 0; kc < 2; kc++)
        af[m][kc] = *(const bf16x8*)(&Alds[(wr * 64 + m * 16 + l15) * 72 + kc * 32 + lg * 8]);
#pragma unroll
    for (int n = 0; n < 4; n++) {
      bf16x8 bfr[2];
#pragma unroll
      for (int kc = 0; kc < 2; kc++)
        bfr[kc] = *(const bf16x8*)(&Blds[(wc * 64 + n * 16 + l15) * 72 + kc * 32 + lg * 8]);
#pragma unroll
      for (int m = 0; m < 4; m++)
#pragma unroll
        for (int kc = 0; kc < 2; kc++)
          acc[m][n] = __builtin_amdgcn_mfma_f32_16x16x32_bf16(af[m][kc], bfr[kc], acc[m][n], 0, 0, 0);
    }
  }

#pragma unroll
  for (int m = 0; m < 4; m++)
#pragma unroll
    for (int n = 0; n < 4; n++)
#pragma unroll
      for (int r = 0; r < 4; r++) {
        int row = r0 + wr * 64 + m * 16 + lg * 4 + r;
        int col = c0 + wc * 64 + n * 16 + l15;
        Y[(size_t)row * D_ + col] = f2bf(acc[m][n][r] * osc);
      }
}

// ---------------- fused attention (32x32 swapped QK^T, raw-barrier pipeline) ----------------
// grid (S/256, H, B); 512 threads = 8 waves; wave w owns q-rows [q0+32w, q0+32w+32),
// q = lane&31 (lane-local softmax state). Compute mappings identical to round-6 (passed).
// Pipeline: next-tile global loads stay IN FLIGHT across the raw s_barrier (no vmcnt
// drain); only lgkmcnt(0) (LDS-write drain) guards the barrier. Writes placed after PV
// so the compiler's counted vmcnt wait lands ~800cy after issue (HBM latency hidden).
__global__ __launch_bounds__(512) void attn_kernel(
    const unsigned short* __restrict__ qh,
    const unsigned short* __restrict__ kh,
    const unsigned short* __restrict__ vh,
    const float* __restrict__ mask,
    float* __restrict__ out) {
  __shared__ __align__(16) unsigned short K_lds[2][64 * 72];
  __shared__ __align__(16) unsigned short V_lds[2][64 * 72];

  const int tid = threadIdx.x;
  const int lane = tid & 63, w = tid >> 6;
  const int l31 = lane & 31, hf = lane >> 5;
  const int q0 = blockIdx.x * 256;
  const int h = blockIdx.y, b = blockIdx.z;
  const size_t head = (size_t)b * S_ * D_ + h * DH_;
  const int qrow = q0 + w * 32 + l31;

  // Q as B-fragments (resident): B[d][q], col q = l31, d = ds*16 + hf*8 + j
  bf16x8 bq[4];
  {
    const unsigned short* qp = qh + head + (size_t)qrow * D_;
#pragma unroll
    for (int ds = 0; ds < 4; ds++) bq[ds] = *(const bf16x8*)(qp + ds * 16 + hf * 8);
  }

  // staging: 512 threads cover 64 rows x 8 chunks; thread -> (row rr, 16B chunk cc)
  const int rr = tid >> 3, cc = tid & 7;
  const unsigned short* kbase = kh + head + (size_t)rr * D_ + cc * 8;
  const unsigned short* vbase = vh + head + (size_t)rr * D_ + cc * 8;

  f32x16 o_acc[2];
#pragma unroll
  for (int dt = 0; dt < 2; dt++)
#pragma unroll
    for (int r = 0; r < 16; r++) o_acc[dt][r] = 0.f;
  float m_r = -INFINITY, l_r = 0.f;

  // prologue: stage tile 0 into buf 0
  {
    bf16x8 kreg = *(const bf16x8*)(kbase);
    bf16x8 vreg = *(const bf16x8*)(vbase);
    *(bf16x8*)(&K_lds[0][rr * 72 + cc * 8]) = kreg;
#pragma unroll
    for (int j = 0; j < 8; j++) {
      int d = cc * 8 + j;
      int byt = (d * 72 + rr) * 2;
      byt ^= ((d >> 3) & 7) << 4;
      *(unsigned short*)((char*)&V_lds[0][0] + byt) = (unsigned short)vreg[j];
    }
    asm volatile("s_waitcnt lgkmcnt(0)" ::: "memory");
    __builtin_amdgcn_s_barrier();
  }

  for (int kt = 0; kt < 32; kt++) {
    const int cur = kt & 1;
    const bool more = (kt + 1 < 32);

    // issue next tile's global loads; they stay in flight across compute
    bf16x8 kreg2, vreg2;
    if (more) {
      const size_t tb = (size_t)(kt + 1) * 64 * D_;
      kreg2 = *(const bf16x8*)(kbase + tb);
      vreg2 = *(const bf16x8*)(vbase + tb);
    }

    // S^T = K · Q^T : lane holds S^T[k][q=l31], k = ct*32 + (r&3) + 8*(r>>2) + 4*hf
    f32x16 sacc[2];
#pragma unroll
    for (int ct = 0; ct < 2; ct++)
#pragma unroll
      for (int r = 0; r < 16; r++) sacc[ct][r] = 0.f;
    __builtin_amdgcn_s_setprio(1);
#pragma unroll
    for (int ds = 0; ds < 4; ds++)
#pragma unroll
      for (int ct = 0; ct < 2; ct++) {
        bf16x8 ak = *(const bf16x8*)(&K_lds[cur][(ct * 32 + l31) * 72 + ds * 16 + hf * 8]);
        sacc[ct] = __builtin_amdgcn_mfma_f32_32x32x16_bf16(ak, bq[ds], sacc[ct], 0, 0, 0);
      }
    __builtin_amdgcn_s_setprio(0);

    // multiplicative mask (scale pre-folded into qh); values in log2 domain
    const float* mrow = mask + (size_t)qrow * S_ + kt * 64 + hf * 4;
#pragma unroll
    for (int ct = 0; ct < 2; ct++)
#pragma unroll
      for (int rq = 0; rq < 4; rq++) {
        float4 mk = *(const float4*)(mrow + ct * 32 + rq * 8);
        sacc[ct][rq * 4 + 0] *= mk.x;
        sacc[ct][rq * 4 + 1] *= mk.y;
        sacc[ct][rq * 4 + 2] *= mk.z;
        sacc[ct][rq * 4 + 3] *= mk.w;
      }

    // online softmax, tree-reduced max (depth 5) + cross-half shfl
    float red[16];
#pragma unroll
    for (int i = 0; i < 16; i++) red[i] = fmaxf(sacc[0][i], sacc[1][i]);
#pragma unroll
    for (int off = 8; off >= 1; off >>= 1)
#pragma unroll
      for (int i = 0; i < off; i++) red[i] = fmaxf(red[i], red[i + off]);
    float tm = fmaxf(red[0], __shfl_xor(red[0], 32));

    float mn;
    if (__any(tm > m_r + 8.0f)) {  // defer-max (THR=8 in log2 domain)
      mn = fmaxf(m_r, tm);
      float alpha = exp2f(m_r - mn);
      m_r = mn;
      l_r *= alpha;
#pragma unroll
      for (int dt = 0; dt < 2; dt++)
#pragma unroll
        for (int r = 0; r < 16; r++) o_acc[dt][r] *= alpha;
    } else {
      mn = m_r;
    }

#pragma unroll
    for (int ct = 0; ct < 2; ct++)
#pragma unroll
      for (int r = 0; r < 16; r++) sacc[ct][r] = exp2f(sacc[ct][r] - mn);

    // tree-reduced sum (depth 5) + cross-half shfl
    float sr[16];
#pragma unroll
    for (int i = 0; i < 16; i++) sr[i] = sacc[0][i] + sacc[1][i];
#pragma unroll
    for (int off = 8; off >= 1; off >>= 1)
#pragma unroll
      for (int i = 0; i < off; i++) sr[i] += sr[i + off];
    l_r += sr[0] + __shfl_xor(sr[0], 32);

    // P -> PV B-fragments (verified r6): cvtpk pairs + shfl_xor(,32) half-exchange
    bf16x8 bfp[4];
#pragma unroll
    for (int s = 0; s < 4; s++) {
      const int ct = s >> 1, rb = (s & 1) * 8;
      int L1 = cvtpk(sacc[ct][rb + 0], sacc[ct][rb + 1]);
      int L2 = cvtpk(sacc[ct][rb + 2], sacc[ct][rb + 3]);
      int H1 = cvtpk(sacc[ct][rb + 4], sacc[ct][rb + 5]);
      int H2 = cvtpk(sacc[ct][rb + 6], sacc[ct][rb + 7]);
      int xL1 = __shfl_xor(L1, 32), xL2 = __shfl_xor(L2, 32);
      int xH1 = __shfl_xor(H1, 32), xH2 = __shfl_xor(H2, 32);
      union { int u[4]; bf16x8 v; } cv;
      cv.u[0] = hf ? xH1 : L1;
      cv.u[1] = hf ? xH2 : L2;
      cv.u[2] = hf ? H1 : xL1;
      cv.u[3] = hf ? H2 : xL2;
      bfp[s] = cv.v;
    }

    // O^T += V^T · P^T : A = V^T[32d][16k] from transposed+swizzled V_lds
    __builtin_amdgcn_s_setprio(1);
#pragma unroll
    for (int dt = 0; dt < 2; dt++) {
      const int d0 = dt * 32 + l31;
      const int bbase = d0 * 144;  // *72 shorts * 2B
      const int swz = ((d0 >> 3) & 7) << 4;
#pragma unroll
      for (int s = 0; s < 4; s++) {
        int byt = (bbase + (s * 16 + hf * 8) * 2) ^ swz;
        bf16x8 av = *(const bf16x8*)((const char*)&V_lds[cur][0] + byt);
        o_acc[dt] = __builtin_amdgcn_mfma_f32_32x32x16_bf16(av, bfp[s], o_acc[dt], 0, 0, 0);
      }
    }
    __builtin_amdgcn_s_setprio(0);

    // stage next tile into buf[cur^1]; compiler inserts counted vmcnt for kreg2/vreg2
    if (more) {
      *(bf16x8*)(&K_lds[cur ^ 1][rr * 72 + cc * 8]) = kreg2;
#pragma unroll
      for (int j = 0; j < 8; j++) {
        int d = cc * 8 + j;
        int byt = (d * 72 + rr) * 2;
        byt ^= ((d >> 3) & 7) << 4;
        *(unsigned short*)((char*)&V_lds[cur ^ 1][0] + byt) = (unsigned short)vreg2[j];
      }
      asm volatile("s_waitcnt lgkmcnt(0)" ::: "memory");  // LDS writes visible
      __builtin_amdgcn_s_barrier();                        // raw: no vmcnt drain
    }
  }

  // epilogue: O^T / l — lane-local q, float4 stores
  const float invl = 1.0f / l_r;
  float* op = out + (size_t)(b * S_ + qrow) * D_ + h * DH_;
#pragma unroll
  for (int dt = 0; dt < 2; dt++)
#pragma unroll
    for (int rq = 0; rq < 4; rq++) {
      float4 ov = { o_acc[dt][rq * 4 + 0] * invl, o_acc[dt][rq * 4 + 1] * invl,
                    o_acc[dt][rq * 4 + 2] * invl, o_acc[dt][rq * 4 + 3] * invl };
      *(float4*)(op + dt * 32 + rq * 8 + hf * 4) = ov;
    }
}

// ---------------- host launch ----------------
extern "C" void kernel_launch(void* const* d_in, const int* in_sizes, int n_in,
                              void* d_out, int out_size, void* d_ws, size_t ws_size,
                              hipStream_t stream) {
  const float* q = (const float*)d_in[0];
  const float* k = (const float*)d_in[1];
  const float* v = (const float*)d_in[2];
  const float* mask = (const float*)d_in[3];
  const float* Wq = (const float*)d_in[4];
  const float* Wk = (const float*)d_in[5];
  const float* Wv = (const float*)d_in[6];

  // ws: qh 16.78M | kh 16.78M | vh 16.78M | Wt 6.29M
  char* ws = (char*)d_ws;
  const size_t SZ_PROJ = (size_t)B_ * S_ * D_ * 2;
  unsigned short* qh = (unsigned short*)(ws);
  unsigned short* kh = (unsigned short*)(ws + SZ_PROJ);
  unsigned short* vh = (unsigned short*)(ws + 2 * SZ_PROJ);
  unsigned short* Wt = (unsigned short*)(ws + 3 * SZ_PROJ);

  wtrans_kernel<<<dim3(D_ / 32, D_ / 32, 3), dim3(32, 8), 0, stream>>>(Wq, Wk, Wv, Wt);
  proj_kernel<<<dim3(D_ / 128, (B_ * S_) / 128, 3), 256, 0, stream>>>(q, k, v, Wt, qh);
  attn_kernel<<<dim3(S_ / 256, H_, B_), 512, 0, stream>>>(qh, kh, vh, mask, (float*)d_out);
}

// Round 8
// 333.583 us; speedup vs baseline: 1.1665x; 1.1665x over previous
//
#include <hip/hip_runtime.h>

#define B_  4
#define S_  2048
#define D_  1024
#define H_  16
#define DH_ 64

typedef __attribute__((ext_vector_type(8))) short bf16x8;
typedef __attribute__((ext_vector_type(4))) float f32x4;
typedef __attribute__((ext_vector_type(16))) float f32x16;
typedef __attribute__((ext_vector_type(4))) unsigned short u16x4;

__device__ __forceinline__ unsigned short f2bf(float f) {
  union { float f; unsigned int u; } x; x.f = f;
  unsigned int u = x.u;
  unsigned int r = (u + 0x7fffu + ((u >> 16) & 1u)) >> 16;  // RNE
  return (unsigned short)r;
}

__device__ __forceinline__ int cvtpk(float lo, float hi) {
  unsigned r;
  asm("v_cvt_pk_bf16_f32 %0, %1, %2" : "=v"(r) : "v"(lo), "v"(hi));
  return (int)r;
}

// ---------------- W (fp32 [k][n]) -> Wt (bf16 [n][k]) ----------------
__global__ __launch_bounds__(256) void wtrans_kernel(const float* __restrict__ W0,
                                                     const float* __restrict__ W1,
                                                     const float* __restrict__ W2,
                                                     unsigned short* __restrict__ Wt) {
  __shared__ float t[32][33];
  const int z = blockIdx.z;
  const float* W = (z == 0) ? W0 : ((z == 1) ? W1 : W2);
  unsigned short* O = Wt + (size_t)z * (D_ * D_);
  const int n0 = blockIdx.x * 32, k0 = blockIdx.y * 32;
  const int tx = threadIdx.x, ty = threadIdx.y;
#pragma unroll
  for (int i = 0; i < 4; i++) t[ty + i * 8][tx] = W[(size_t)(k0 + ty + i * 8) * D_ + n0 + tx];
  __syncthreads();
#pragma unroll
  for (int i = 0; i < 4; i++)
    O[(size_t)(n0 + ty + i * 8) * D_ + k0 + tx] = f2bf(t[tx][ty + i * 8]);
}

// ---------------- projection GEMM: Y(bf16) = X(fp32) @ W, via Wt ----------------
// For z==0 (q), folds 0.125*log2e (attn scale, log2 domain) into the output.
__global__ __launch_bounds__(256) void proj_kernel(const float* __restrict__ X0,
                                                   const float* __restrict__ X1,
                                                   const float* __restrict__ X2,
                                                   const unsigned short* __restrict__ Wt,
                                                   unsigned short* __restrict__ Y0) {
  __shared__ unsigned short Alds[128 * 72];
  __shared__ unsigned short Blds[128 * 72];
  const int z = blockIdx.z;
  const float* X = (z == 0) ? X0 : ((z == 1) ? X1 : X2);
  const unsigned short* Wz = Wt + (size_t)z * (D_ * D_);
  unsigned short* Y = Y0 + (size_t)z * ((size_t)B_ * S_ * D_);
  const float osc = (z == 0) ? 0.18033688f : 1.0f;  // 0.125 * log2(e)

  const int tid = threadIdx.x;
  const int lane = tid & 63, w = tid >> 6;
  const int wr = w >> 1, wc = w & 1;
  const int l15 = lane & 15, lg = lane >> 4;
  const int r0 = blockIdx.y * 128, c0 = blockIdx.x * 128;

  f32x4 acc[4][4];
#pragma unroll
  for (int m = 0; m < 4; m++)
#pragma unroll
    for (int n = 0; n < 4; n++) acc[m][n] = (f32x4){0.f, 0.f, 0.f, 0.f};

  for (int kt = 0; kt < 16; ++kt) {
    __syncthreads();
    {
      const int rr = tid >> 4, cf = (tid & 15) * 4;
#pragma unroll
      for (int p = 0; p < 8; p++) {
        int row = rr + p * 16;
        float4 xv = *(const float4*)(X + (size_t)(r0 + row) * D_ + kt * 64 + cf);
        u16x4 bb = { f2bf(xv.x), f2bf(xv.y), f2bf(xv.z), f2bf(xv.w) };
        *(u16x4*)(&Alds[row * 72 + cf]) = bb;
      }
      const int rb = tid >> 3, cb = tid & 7;
#pragma unroll
      for (int p = 0; p < 4; p++) {
        int row = rb + p * 32;
        bf16x8 wv = *(const bf16x8*)(Wz + (size_t)(c0 + row) * D_ + kt * 64 + cb * 8);
        *(bf16x8*)(&Blds[row * 72 + cb * 8]) = wv;
      }
    }
    __syncthreads();

    bf16x8 af[4][2];
#pragma unroll
    for (int m = 0; m < 4; m++)
#pragma unroll
      for (int kc = 0; kc < 2; kc++)
        af[m][kc] = *(const bf16x8*)(&Alds[(wr * 64 + m * 16 + l15) * 72 + kc * 32 + lg * 8]);
#pragma unroll
    for (int n = 0; n < 4; n++) {
      bf16x8 bfr[2];
#pragma unroll
      for (int kc = 0; kc < 2; kc++)
        bfr[kc] = *(const bf16x8*)(&Blds[(wc * 64 + n * 16 + l15) * 72 + kc * 32 + lg * 8]);
#pragma unroll
      for (int m = 0; m < 4; m++)
#pragma unroll
        for (int kc = 0; kc < 2; kc++)
          acc[m][n] = __builtin_amdgcn_mfma_f32_16x16x32_bf16(af[m][kc], bfr[kc], acc[m][n], 0, 0, 0);
    }
  }

#pragma unroll
  for (int m = 0; m < 4; m++)
#pragma unroll
    for (int n = 0; n < 4; n++)
#pragma unroll
      for (int r = 0; r < 4; r++) {
        int row = r0 + wr * 64 + m * 16 + lg * 4 + r;
        int col = c0 + wc * 64 + n * 16 + l15;
        Y[(size_t)row * D_ + col] = f2bf(acc[m][n][r] * osc);
      }
}

// ---------------- fused attention (32x32 swapped QK^T, bottom-barrier pipeline) ----------------
// grid (S/128, H, B); 256 thr = 4 waves; wave w owns q-rows [q0+32w, q0+32w+32),
// q = lane&31 (lane-local softmax state). Compute mappings identical to round-6 (passed).
// Loop shape: [pinned prefetch issue | sched_barrier | compute(buf cur) |
//              counted-vmcnt (compiler) | stage buf cur^1 | __syncthreads].
// Loads complete under ~800cy of compute; the barrier's vmcnt drain is then free.
__global__ __launch_bounds__(256) void attn_kernel(
    const unsigned short* __restrict__ qh,
    const unsigned short* __restrict__ kh,
    const unsigned short* __restrict__ vh,
    const float* __restrict__ mask,
    float* __restrict__ out) {
  __shared__ __align__(16) unsigned short K_lds[2][64 * 72];
  __shared__ __align__(16) unsigned short V_lds[2][64 * 72];

  const int tid = threadIdx.x;
  const int lane = tid & 63, w = tid >> 6;
  const int l31 = lane & 31, hf = lane >> 5;
  const int q0 = blockIdx.x * 128;
  const int h = blockIdx.y, b = blockIdx.z;
  const size_t head = (size_t)b * S_ * D_ + h * DH_;
  const int qrow = q0 + w * 32 + l31;

  // Q as B-fragments (resident): B[d][q], col q = l31, d = ds*16 + hf*8 + j
  bf16x8 bq[4];
  {
    const unsigned short* qp = qh + head + (size_t)qrow * D_;
#pragma unroll
    for (int ds = 0; ds < 4; ds++) bq[ds] = *(const bf16x8*)(qp + ds * 16 + hf * 8);
  }

  // staging (verified r3/r5/r6): thread covers rows rr, rr+32; 16B chunk at col cc*8
  const int rr = tid >> 3, cc = tid & 7;
  const unsigned short* kbase = kh + head + (size_t)rr * D_ + cc * 8;
  const unsigned short* vbase = vh + head + (size_t)rr * D_ + cc * 8;

  f32x16 o_acc[2];
#pragma unroll
  for (int dt = 0; dt < 2; dt++)
#pragma unroll
    for (int r = 0; r < 16; r++) o_acc[dt][r] = 0.f;
  float m_r = -INFINITY, l_r = 0.f;

  // prologue: stage tile 0 into buf 0
  {
#pragma unroll
    for (int p = 0; p < 2; p++) {
      bf16x8 kreg = *(const bf16x8*)(kbase + (size_t)p * 32 * D_);
      bf16x8 vreg = *(const bf16x8*)(vbase + (size_t)p * 32 * D_);
      int row = rr + p * 32;
      *(bf16x8*)(&K_lds[0][row * 72 + cc * 8]) = kreg;
#pragma unroll
      for (int j = 0; j < 8; j++) {
        int d = cc * 8 + j;
        int byt = (d * 72 + row) * 2;
        byt ^= ((d >> 3) & 7) << 4;
        *(unsigned short*)((char*)&V_lds[0][0] + byt) = (unsigned short)vreg[j];
      }
    }
    __syncthreads();
  }

  for (int kt = 0; kt < 32; kt++) {
    const int cur = kt & 1;
    const bool more = (kt + 1 < 32);

    // pinned prefetch: unconditional (clamped addr), sched_barrier stops sinking
    const size_t tb = (size_t)(more ? kt + 1 : kt) * 64 * D_;
    bf16x8 kreg2[2], vreg2[2];
#pragma unroll
    for (int p = 0; p < 2; p++) {
      kreg2[p] = *(const bf16x8*)(kbase + tb + (size_t)p * 32 * D_);
      vreg2[p] = *(const bf16x8*)(vbase + tb + (size_t)p * 32 * D_);
    }
    __builtin_amdgcn_sched_barrier(0);

    // S^T = K · Q^T : lane holds S^T[k][q=l31], k = ct*32 + (r&3) + 8*(r>>2) + 4*hf
    f32x16 sacc[2];
#pragma unroll
    for (int ct = 0; ct < 2; ct++)
#pragma unroll
      for (int r = 0; r < 16; r++) sacc[ct][r] = 0.f;
    __builtin_amdgcn_s_setprio(1);
#pragma unroll
    for (int ds = 0; ds < 4; ds++)
#pragma unroll
      for (int ct = 0; ct < 2; ct++) {
        bf16x8 ak = *(const bf16x8*)(&K_lds[cur][(ct * 32 + l31) * 72 + ds * 16 + hf * 8]);
        sacc[ct] = __builtin_amdgcn_mfma_f32_32x32x16_bf16(ak, bq[ds], sacc[ct], 0, 0, 0);
      }
    __builtin_amdgcn_s_setprio(0);

    // multiplicative mask (scale pre-folded into qh); values in log2 domain
    const float* mrow = mask + (size_t)qrow * S_ + kt * 64 + hf * 4;
#pragma unroll
    for (int ct = 0; ct < 2; ct++)
#pragma unroll
      for (int rq = 0; rq < 4; rq++) {
        float4 mk = *(const float4*)(mrow + ct * 32 + rq * 8);
        sacc[ct][rq * 4 + 0] *= mk.x;
        sacc[ct][rq * 4 + 1] *= mk.y;
        sacc[ct][rq * 4 + 2] *= mk.z;
        sacc[ct][rq * 4 + 3] *= mk.w;
      }

    // online softmax, tree-reduced max (depth 5) + cross-half shfl
    float red[16];
#pragma unroll
    for (int i = 0; i < 16; i++) red[i] = fmaxf(sacc[0][i], sacc[1][i]);
#pragma unroll
    for (int off = 8; off >= 1; off >>= 1)
#pragma unroll
      for (int i = 0; i < off; i++) red[i] = fmaxf(red[i], red[i + off]);
    float tm = fmaxf(red[0], __shfl_xor(red[0], 32));

    float mn;
    if (__any(tm > m_r + 8.0f)) {  // defer-max (THR=8 in log2 domain)
      mn = fmaxf(m_r, tm);
      float alpha = exp2f(m_r - mn);
      m_r = mn;
      l_r *= alpha;
#pragma unroll
      for (int dt = 0; dt < 2; dt++)
#pragma unroll
        for (int r = 0; r < 16; r++) o_acc[dt][r] *= alpha;
    } else {
      mn = m_r;
    }

#pragma unroll
    for (int ct = 0; ct < 2; ct++)
#pragma unroll
      for (int r = 0; r < 16; r++) sacc[ct][r] = exp2f(sacc[ct][r] - mn);

    // tree-reduced sum (depth 5) + cross-half shfl
    float sr[16];
#pragma unroll
    for (int i = 0; i < 16; i++) sr[i] = sacc[0][i] + sacc[1][i];
#pragma unroll
    for (int off = 8; off >= 1; off >>= 1)
#pragma unroll
      for (int i = 0; i < off; i++) sr[i] += sr[i + off];
    l_r += sr[0] + __shfl_xor(sr[0], 32);

    // P -> PV B-fragments (verified r6): cvtpk pairs + shfl_xor(,32) half-exchange
    bf16x8 bfp[4];
#pragma unroll
    for (int s = 0; s < 4; s++) {
      const int ct = s >> 1, rb = (s & 1) * 8;
      int L1 = cvtpk(sacc[ct][rb + 0], sacc[ct][rb + 1]);
      int L2 = cvtpk(sacc[ct][rb + 2], sacc[ct][rb + 3]);
      int H1 = cvtpk(sacc[ct][rb + 4], sacc[ct][rb + 5]);
      int H2 = cvtpk(sacc[ct][rb + 6], sacc[ct][rb + 7]);
      int xL1 = __shfl_xor(L1, 32), xL2 = __shfl_xor(L2, 32);
      int xH1 = __shfl_xor(H1, 32), xH2 = __shfl_xor(H2, 32);
      union { int u[4]; bf16x8 v; } cv;
      cv.u[0] = hf ? xH1 : L1;
      cv.u[1] = hf ? xH2 : L2;
      cv.u[2] = hf ? H1 : xL1;
      cv.u[3] = hf ? H2 : xL2;
      bfp[s] = cv.v;
    }

    // O^T += V^T · P^T : A = V^T[32d][16k] from transposed+swizzled V_lds
    __builtin_amdgcn_s_setprio(1);
#pragma unroll
    for (int dt = 0; dt < 2; dt++) {
      const int d0 = dt * 32 + l31;
      const int bbase = d0 * 144;  // *72 shorts * 2B
      const int swz = ((d0 >> 3) & 7) << 4;
#pragma unroll
      for (int s = 0; s < 4; s++) {
        int byt = (bbase + (s * 16 + hf * 8) * 2) ^ swz;
        bf16x8 av = *(const bf16x8*)((const char*)&V_lds[cur][0] + byt);
        o_acc[dt] = __builtin_amdgcn_mfma_f32_32x32x16_bf16(av, bfp[s], o_acc[dt], 0, 0, 0);
      }
    }
    __builtin_amdgcn_s_setprio(0);

    // stage next tile (compiler emits counted vmcnt for kreg2/vreg2 here — they
    // completed during compute), then one barrier protecting buf[cur^1] reuse
    if (more) {
#pragma unroll
      for (int p = 0; p < 2; p++) {
        int row = rr + p * 32;
        *(bf16x8*)(&K_lds[cur ^ 1][row * 72 + cc * 8]) = kreg2[p];
#pragma unroll
        for (int j = 0; j < 8; j++) {
          int d = cc * 8 + j;
          int byt = (d * 72 + row) * 2;
          byt ^= ((d >> 3) & 7) << 4;
          *(unsigned short*)((char*)&V_lds[cur ^ 1][0] + byt) = (unsigned short)vreg2[p][j];
        }
      }
      __syncthreads();
    }
  }

  // epilogue: O^T / l — lane-local q, float4 stores
  const float invl = 1.0f / l_r;
  float* op = out + (size_t)(b * S_ + qrow) * D_ + h * DH_;
#pragma unroll
  for (int dt = 0; dt < 2; dt++)
#pragma unroll
    for (int rq = 0; rq < 4; rq++) {
      float4 ov = { o_acc[dt][rq * 4 + 0] * invl, o_acc[dt][rq * 4 + 1] * invl,
                    o_acc[dt][rq * 4 + 2] * invl, o_acc[dt][rq * 4 + 3] * invl };
      *(float4*)(op + dt * 32 + rq * 8 + hf * 4) = ov;
    }
}

// ---------------- host launch ----------------
extern "C" void kernel_launch(void* const* d_in, const int* in_sizes, int n_in,
                              void* d_out, int out_size, void* d_ws, size_t ws_size,
                              hipStream_t stream) {
  const float* q = (const float*)d_in[0];
  const float* k = (const float*)d_in[1];
  const float* v = (const float*)d_in[2];
  const float* mask = (const float*)d_in[3];
  const float* Wq = (const float*)d_in[4];
  const float* Wk = (const float*)d_in[5];
  const float* Wv = (const float*)d_in[6];

  // ws: qh 16.78M | kh 16.78M | vh 16.78M | Wt 6.29M
  char* ws = (char*)d_ws;
  const size_t SZ_PROJ = (size_t)B_ * S_ * D_ * 2;
  unsigned short* qh = (unsigned short*)(ws);
  unsigned short* kh = (unsigned short*)(ws + SZ_PROJ);
  unsigned short* vh = (unsigned short*)(ws + 2 * SZ_PROJ);
  unsigned short* Wt = (unsigned short*)(ws + 3 * SZ_PROJ);

  wtrans_kernel<<<dim3(D_ / 32, D_ / 32, 3), dim3(32, 8), 0, stream>>>(Wq, Wk, Wv, Wt);
  proj_kernel<<<dim3(D_ / 128, (B_ * S_) / 128, 3), 256, 0, stream>>>(q, k, v, Wt, qh);
  attn_kernel<<<dim3(S_ / 128, H_, B_), 256, 0, stream>>>(qh, kh, vh, mask, (float*)d_out);
}